// Round 3
// baseline (579.836 us; speedup 1.0000x reference)
//
#include <hip/hip_runtime.h>
#include <hip/hip_bf16.h>

typedef __attribute__((ext_vector_type(8))) short short8;
typedef __attribute__((ext_vector_type(4))) float floatx4;
typedef unsigned short u16;

#define B_SZ 4
#define NH   16
#define SEQ  2048
#define DM   1024
#define DK   64
#define M_ROWS (B_SZ * SEQ)   // 8192

__device__ __forceinline__ u16 f2bf(float f) {
  unsigned u = __float_as_uint(f);
  u += 0x7fff + ((u >> 16) & 1);   // RNE
  return (u16)(u >> 16);
}
__device__ __forceinline__ float bf2f(u16 u) {
  return __uint_as_float(((unsigned)u) << 16);
}

// ---------------------------------------------------------------------------
// 128x128 GEMM core, fp32 inputs: C = A (MxK f32) * W^T (W NxK f32).
// Stages tiles into LDS as bf16 (RNE). 256 thr = 4 waves (2x2), each wave
// 64x64 via 4x4 grid of 16x16x32 bf16 MFMA, fp32 accumulate.
// ---------------------------------------------------------------------------
__device__ __forceinline__ void gemm_core_f32(
    const float* __restrict__ A, const float* __restrict__ W,
    int m0, int n0, int K, floatx4 acc[4][4])
{
  __shared__ short As[128 * 32];
  __shared__ short Bs[128 * 32];

  const int tid  = threadIdx.x;
  const int w    = tid >> 6;
  const int lane = tid & 63;
  const int wm   = w >> 1, wn = w & 1;
  const int quad = lane >> 4, l16 = lane & 15;

#pragma unroll
  for (int i = 0; i < 4; ++i)
#pragma unroll
    for (int j = 0; j < 4; ++j)
      acc[i][j] = floatx4{0.f, 0.f, 0.f, 0.f};

  const int nIter = K >> 5;
  for (int kt = 0; kt < nIter; ++kt) {
    const int kk = kt * 32;
    __syncthreads();
#pragma unroll
    for (int c = 0; c < 2; ++c) {
      const int idx = tid + c * 256;          // 0..511
      const int row = idx >> 2;               // 0..127
      const int col = (idx & 3) * 8;          // 0,8,16,24 (elements)
      const float* pa = A + (size_t)(m0 + row) * K + kk + col;
      const float* pw = W + (size_t)(n0 + row) * K + kk + col;
      floatx4 a0 = *(const floatx4*)pa, a1 = *(const floatx4*)(pa + 4);
      floatx4 b0 = *(const floatx4*)pw, b1 = *(const floatx4*)(pw + 4);
      short8 sa, sb;
#pragma unroll
      for (int e = 0; e < 4; ++e) {
        sa[e] = (short)f2bf(a0[e]); sa[4 + e] = (short)f2bf(a1[e]);
        sb[e] = (short)f2bf(b0[e]); sb[4 + e] = (short)f2bf(b1[e]);
      }
      *(short8*)(As + row * 32 + col) = sa;
      *(short8*)(Bs + row * 32 + col) = sb;
    }
    __syncthreads();

    short8 afr[4], bfr[4];
#pragma unroll
    for (int t = 0; t < 4; ++t) {
      afr[t] = *(const short8*)(As + (wm * 64 + t * 16 + l16) * 32 + quad * 8);
      bfr[t] = *(const short8*)(Bs + (wn * 64 + t * 16 + l16) * 32 + quad * 8);
    }
#pragma unroll
    for (int i = 0; i < 4; ++i)
#pragma unroll
      for (int j = 0; j < 4; ++j)
        acc[i][j] = __builtin_amdgcn_mfma_f32_16x16x32_bf16(afr[i], bfr[j], acc[i][j], 0, 0, 0);
  }
}

// Same core but A is already bf16 (u16) and W is fp32.
__device__ __forceinline__ void gemm_core_mixed(
    const u16* __restrict__ A, const float* __restrict__ W,
    int m0, int n0, int K, floatx4 acc[4][4])
{
  __shared__ short As[128 * 32];
  __shared__ short Bs[128 * 32];

  const int tid  = threadIdx.x;
  const int w    = tid >> 6;
  const int lane = tid & 63;
  const int wm   = w >> 1, wn = w & 1;
  const int quad = lane >> 4, l16 = lane & 15;

#pragma unroll
  for (int i = 0; i < 4; ++i)
#pragma unroll
    for (int j = 0; j < 4; ++j)
      acc[i][j] = floatx4{0.f, 0.f, 0.f, 0.f};

  const int nIter = K >> 5;
  for (int kt = 0; kt < nIter; ++kt) {
    const int kk = kt * 32;
    __syncthreads();
#pragma unroll
    for (int c = 0; c < 2; ++c) {
      const int idx = tid + c * 256;
      const int row = idx >> 2;
      const int col = (idx & 3) * 8;
      *(short8*)(As + row * 32 + col) =
          *(const short8*)(A + (size_t)(m0 + row) * K + kk + col);
      const float* pw = W + (size_t)(n0 + row) * K + kk + col;
      floatx4 b0 = *(const floatx4*)pw, b1 = *(const floatx4*)(pw + 4);
      short8 sb;
#pragma unroll
      for (int e = 0; e < 4; ++e) { sb[e] = (short)f2bf(b0[e]); sb[4 + e] = (short)f2bf(b1[e]); }
      *(short8*)(Bs + row * 32 + col) = sb;
    }
    __syncthreads();

    short8 afr[4], bfr[4];
#pragma unroll
    for (int t = 0; t < 4; ++t) {
      afr[t] = *(const short8*)(As + (wm * 64 + t * 16 + l16) * 32 + quad * 8);
      bfr[t] = *(const short8*)(Bs + (wn * 64 + t * 16 + l16) * 32 + quad * 8);
    }
#pragma unroll
    for (int i = 0; i < 4; ++i)
#pragma unroll
      for (int j = 0; j < 4; ++j)
        acc[i][j] = __builtin_amdgcn_mfma_f32_16x16x32_bf16(afr[i], bfr[j], acc[i][j], 0, 0, 0);
  }
}

// ---------------------------------------------------------------------------
// Fused QKV projection. grid = (64, 24): y/8 selects Q/K/V, y%8 = n-block.
// Q,K written bf16 as (b,h,s,d); V written bf16 transposed as (b,h,d,s).
// ---------------------------------------------------------------------------
__global__ __launch_bounds__(256, 2)
void qkv_kernel(const float* __restrict__ x,
                const float* __restrict__ Wq, const float* __restrict__ Wk, const float* __restrict__ Wv,
                const float* __restrict__ bq, const float* __restrict__ bk, const float* __restrict__ bv,
                u16* __restrict__ Qo, u16* __restrict__ Ko, u16* __restrict__ Vto)
{
  const int mat = blockIdx.y >> 3;
  const int m0  = blockIdx.x * 128;
  const int n0  = (blockIdx.y & 7) * 128;
  const float* W    = (mat == 0) ? Wq : (mat == 1) ? Wk : Wv;
  const float* bias = (mat == 0) ? bq : (mat == 1) ? bk : bv;
  u16* dst          = (mat == 0) ? Qo : (mat == 1) ? Ko : Vto;

  floatx4 acc[4][4];
  gemm_core_f32(x, W, m0, n0, DM, acc);

  const int tid = threadIdx.x;
  const int w = tid >> 6, lane = tid & 63;
  const int wm = w >> 1, wn = w & 1, quad = lane >> 4, l16 = lane & 15;

#pragma unroll
  for (int nt = 0; nt < 4; ++nt) {
    const int n = n0 + wn * 64 + nt * 16 + l16;
    const float bb = bias[n];
    const int h = n >> 6, d = n & 63;
#pragma unroll
    for (int mt = 0; mt < 4; ++mt)
#pragma unroll
      for (int r = 0; r < 4; ++r) {
        const int m = m0 + wm * 64 + mt * 16 + quad * 4 + r;
        const int b = m >> 11, s = m & 2047;
        const float v = acc[mt][nt][r] + bb;
        size_t off;
        if (mat < 2) off = ((size_t)(b * NH + h) * SEQ + s) * DK + d;   // (b,h,s,d)
        else         off = ((size_t)(b * NH + h) * DK + d) * SEQ + s;   // (b,h,d,s)
        dst[off] = f2bf(v);
      }
  }
}

// ---------------------------------------------------------------------------
// Flash attention, causal. grid = (S/64 q-tiles, B*H). 256 thr = 4 waves,
// each wave owns 16 query rows; 64-key tiles staged in LDS. bf16 in/out.
// ---------------------------------------------------------------------------
__global__ __launch_bounds__(256, 2)
void attn_kernel(const u16* __restrict__ Q, const u16* __restrict__ Kx,
                 const u16* __restrict__ Vt, u16* __restrict__ O)
{
  __shared__ short Ks[64 * 64];
  __shared__ short Vs[64 * 64];      // Vs[d][s] (already transposed in global)
  __shared__ short Ps[4 * 16 * 64];  // per-wave P round-trip

  const int qt = blockIdx.x, bh = blockIdx.y;
  const int tid = threadIdx.x;
  const int w = tid >> 6, lane = tid & 63;
  const int quad = lane >> 4, l16 = lane & 15;
  const int q0 = qt * 64;

  const u16* Qh = Q  + (size_t)bh * SEQ * DK;
  const u16* Kh = Kx + (size_t)bh * SEQ * DK;
  const u16* Vh = Vt + (size_t)bh * DK * SEQ;

  const int qrow = q0 + w * 16 + l16;
  const short8 qf0 = *(const short8*)(Qh + (size_t)qrow * DK + quad * 8);
  const short8 qf1 = *(const short8*)(Qh + (size_t)qrow * DK + 32 + quad * 8);

  float m_i[4] = {-1e30f, -1e30f, -1e30f, -1e30f};
  float l_i[4] = {0.f, 0.f, 0.f, 0.f};
  floatx4 o[4];
#pragma unroll
  for (int dt = 0; dt < 4; ++dt) o[dt] = floatx4{0.f, 0.f, 0.f, 0.f};

  for (int kt = 0; kt <= qt; ++kt) {
    const int k0 = kt * 64;
    __syncthreads();   // Ks/Vs still read at end of previous iteration
#pragma unroll
    for (int c = 0; c < 2; ++c) {
      const int idx = tid + c * 256;
      const int row = idx >> 3;               // 0..63
      const int col = (idx & 7) * 8;          // 0..56
      *(short8*)(Ks + row * 64 + col) = *(const short8*)(Kh + (size_t)(k0 + row) * DK + col);
      *(short8*)(Vs + row * 64 + col) = *(const short8*)(Vh + (size_t)row * SEQ + k0 + col);
    }
    __syncthreads();

    floatx4 sc[4];
#pragma unroll
    for (int nt = 0; nt < 4; ++nt) {
      const short8 kf0 = *(const short8*)(Ks + (nt * 16 + l16) * 64 + quad * 8);
      const short8 kf1 = *(const short8*)(Ks + (nt * 16 + l16) * 64 + 32 + quad * 8);
      floatx4 z = floatx4{0.f, 0.f, 0.f, 0.f};
      z = __builtin_amdgcn_mfma_f32_16x16x32_bf16(qf0, kf0, z, 0, 0, 0);
      z = __builtin_amdgcn_mfma_f32_16x16x32_bf16(qf1, kf1, z, 0, 0, 0);
      sc[nt] = z;
    }

#pragma unroll
    for (int nt = 0; nt < 4; ++nt)
#pragma unroll
      for (int r = 0; r < 4; ++r) {
        float s = sc[nt][r] * 0.125f;   // 1/sqrt(64)
        if (kt == qt) {
          const int col = k0 + nt * 16 + l16;
          const int row = q0 + w * 16 + quad * 4 + r;
          if (col > row) s = -1e30f;
        }
        sc[nt][r] = s;
      }

    float al[4];
#pragma unroll
    for (int r = 0; r < 4; ++r) {
      float mx = fmaxf(fmaxf(sc[0][r], sc[1][r]), fmaxf(sc[2][r], sc[3][r]));
#pragma unroll
      for (int off = 1; off < 16; off <<= 1)
        mx = fmaxf(mx, __shfl_xor(mx, off));
      const float mnew = fmaxf(m_i[r], mx);
      al[r] = __expf(m_i[r] - mnew);
      m_i[r] = mnew;
    }
#pragma unroll
    for (int nt = 0; nt < 4; ++nt)
#pragma unroll
      for (int r = 0; r < 4; ++r)
        sc[nt][r] = __expf(sc[nt][r] - m_i[r]);
#pragma unroll
    for (int r = 0; r < 4; ++r) {
      float rs = sc[0][r] + sc[1][r] + sc[2][r] + sc[3][r];
#pragma unroll
      for (int off = 1; off < 16; off <<= 1)
        rs += __shfl_xor(rs, off);
      l_i[r] = l_i[r] * al[r] + rs;
    }
#pragma unroll
    for (int dt = 0; dt < 4; ++dt)
#pragma unroll
      for (int r = 0; r < 4; ++r)
        o[dt][r] *= al[r];

    short* Pw = Ps + w * (16 * 64);
#pragma unroll
    for (int nt = 0; nt < 4; ++nt)
#pragma unroll
      for (int r = 0; r < 4; ++r)
        Pw[(quad * 4 + r) * 64 + nt * 16 + l16] = (short)f2bf(sc[nt][r]);
    __syncthreads();

    const short8 pf0 = *(const short8*)(Pw + l16 * 64 + quad * 8);
    const short8 pf1 = *(const short8*)(Pw + l16 * 64 + 32 + quad * 8);
#pragma unroll
    for (int dt = 0; dt < 4; ++dt) {
      const short8 vf0 = *(const short8*)(Vs + (dt * 16 + l16) * 64 + quad * 8);
      const short8 vf1 = *(const short8*)(Vs + (dt * 16 + l16) * 64 + 32 + quad * 8);
      o[dt] = __builtin_amdgcn_mfma_f32_16x16x32_bf16(pf0, vf0, o[dt], 0, 0, 0);
      o[dt] = __builtin_amdgcn_mfma_f32_16x16x32_bf16(pf1, vf1, o[dt], 0, 0, 0);
    }
  }

  // O'[b, s, h*64+d] bf16, row-major (8192 x 1024)
  const int b = bh >> 4, h = bh & 15;
#pragma unroll
  for (int r = 0; r < 4; ++r) {
    const float inv = 1.0f / fmaxf(l_i[r], 1e-20f);
    const int row = q0 + w * 16 + quad * 4 + r;
    const size_t base = ((size_t)b * SEQ + row) * DM + h * DK;
#pragma unroll
    for (int dt = 0; dt < 4; ++dt)
      O[base + dt * 16 + l16] = f2bf(o[dt][r] * inv);
  }
}

// ---------------------------------------------------------------------------
// Output projection: out = O' @ Wo^T + bo, fp32 output. grid = (64, 8).
// ---------------------------------------------------------------------------
__global__ __launch_bounds__(256, 2)
void oproj_kernel(const u16* __restrict__ A, const float* __restrict__ Wo,
                  const float* __restrict__ bo, float* __restrict__ out)
{
  const int m0 = blockIdx.x * 128, n0 = blockIdx.y * 128;
  floatx4 acc[4][4];
  gemm_core_mixed(A, Wo, m0, n0, DM, acc);

  const int tid = threadIdx.x;
  const int w = tid >> 6, lane = tid & 63;
  const int wm = w >> 1, wn = w & 1, quad = lane >> 4, l16 = lane & 15;

#pragma unroll
  for (int nt = 0; nt < 4; ++nt) {
    const int n = n0 + wn * 64 + nt * 16 + l16;
    const float bb = bo[n];
#pragma unroll
    for (int mt = 0; mt < 4; ++mt)
#pragma unroll
      for (int r = 0; r < 4; ++r) {
        const int m = m0 + wm * 64 + mt * 16 + quad * 4 + r;
        out[(size_t)m * DM + n] = acc[mt][nt][r] + bb;
      }
  }
}

extern "C" void kernel_launch(void* const* d_in, const int* in_sizes, int n_in,
                              void* d_out, int out_size, void* d_ws, size_t ws_size,
                              hipStream_t stream)
{
  const float* x  = (const float*)d_in[0];
  const float* Wq = (const float*)d_in[1];
  const float* bq = (const float*)d_in[2];
  const float* Wk = (const float*)d_in[3];
  const float* bk = (const float*)d_in[4];
  const float* Wv = (const float*)d_in[5];
  const float* bv = (const float*)d_in[6];
  const float* Wo = (const float*)d_in[7];
  const float* bo = (const float*)d_in[8];
  float* out = (float*)d_out;

  u16* qws  = (u16*)d_ws;                       // (b,h,s,d)  bf16, 16 MiB
  u16* kws  = qws  + (size_t)M_ROWS * DM;       // (b,h,s,d)  bf16, 16 MiB
  u16* vtws = kws  + (size_t)M_ROWS * DM;       // (b,h,d,s)  bf16, 16 MiB
  u16* ows  = vtws + (size_t)M_ROWS * DM;       // (b,s,h*d)  bf16, 16 MiB

  qkv_kernel <<<dim3(64, 24), 256, 0, stream>>>(x, Wq, Wk, Wv, bq, bk, bv, qws, kws, vtws);
  attn_kernel<<<dim3(32, 64), 256, 0, stream>>>(qws, kws, vtws, ows);
  oproj_kernel<<<dim3(64, 8), 256, 0, stream>>>(ows, Wo, bo, out);
}

// Round 5
// 294.246 us; speedup vs baseline: 1.9706x; 1.9706x over previous
//
#include <hip/hip_runtime.h>
#include <hip/hip_bf16.h>

typedef __attribute__((ext_vector_type(8))) short short8;
typedef __attribute__((ext_vector_type(4))) short short4v;
typedef __attribute__((ext_vector_type(4))) float floatx4;
typedef unsigned short u16;

#define B_SZ 4
#define NH   16
#define SEQ  2048
#define DM   1024
#define DK   64
#define M_ROWS (B_SZ * SEQ)   // 8192

__device__ __forceinline__ u16 f2bf(float f) {
  unsigned u = __float_as_uint(f);
  u += 0x7fff + ((u >> 16) & 1);   // RNE
  return (u16)(u >> 16);
}

// async global->LDS: dest = wave-uniform base + lane*16B (verified constraint)
__device__ __forceinline__ void async_copy16(const u16* g, const short* lds) {
  __builtin_amdgcn_global_load_lds(
      (const __attribute__((address_space(1))) void*)g,
      (__attribute__((address_space(3))) void*)lds,
      16, 0, 0);
}

// ---------------------------------------------------------------------------
// fp32 -> bf16 convert (grid-stride, float4 -> 4x bf16)
// ---------------------------------------------------------------------------
__global__ __launch_bounds__(256)
void cvt_kernel(const float* __restrict__ in, u16* __restrict__ out, int n4)
{
  for (int i = blockIdx.x * 256 + threadIdx.x; i < n4; i += gridDim.x * 256) {
    floatx4 v = ((const floatx4*)in)[i];
    short4v s;
#pragma unroll
    for (int e = 0; e < 4; ++e) s[e] = (short)f2bf(v[e]);
    ((short4v*)out)[i] = s;
  }
}

// ---------------------------------------------------------------------------
// 128x128 GEMM core: C = A(bf16, MxK row-major) * W^T (W fp32, NxK row-major).
// A staged via global_load_lds width=16; W loaded fp32, converted, ds_write.
// 4 waves (2x2), each 64x64 via 4x4 of 16x16x32 bf16 MFMA.
// ---------------------------------------------------------------------------
__device__ __forceinline__ void gemm_core_async(
    const u16* __restrict__ A, const float* __restrict__ W,
    int m0, int n0, floatx4 acc[4][4])
{
  __shared__ short As[128 * 32];     // stride 32 (async: no padding allowed)
  __shared__ short Bs[128 * 40];     // stride 40: breaks bank conflicts

  const int tid  = threadIdx.x;
  const int w    = tid >> 6;
  const int lane = tid & 63;
  const int wm   = w >> 1, wn = w & 1;
  const int quad = lane >> 4, l16 = lane & 15;
  const int r4   = lane >> 2, c4 = lane & 3;

#pragma unroll
  for (int i = 0; i < 4; ++i)
#pragma unroll
    for (int j = 0; j < 4; ++j)
      acc[i][j] = floatx4{0.f, 0.f, 0.f, 0.f};

  for (int kt = 0; kt < (DM >> 5); ++kt) {
    const int kk = kt * 32;
    __syncthreads();
    // A-side: async, 2 calls/wave, 16 rows x 64B each
#pragma unroll
    for (int c = 0; c < 2; ++c) {
      const int rowA = w * 32 + c * 16;   // wave-uniform
      async_copy16(A + (size_t)(m0 + rowA + r4) * DM + kk + c4 * 8, As + rowA * 32);
    }
    // W-side: fp32 load + convert + ds_write (Bs stride 40)
#pragma unroll
    for (int c = 0; c < 2; ++c) {
      const int idx = tid + c * 256;
      const int row = idx >> 2;
      const int col = (idx & 3) * 8;
      const float* pw = W + (size_t)(n0 + row) * DM + kk + col;
      floatx4 b0 = *(const floatx4*)pw, b1 = *(const floatx4*)(pw + 4);
      short8 sb;
#pragma unroll
      for (int e = 0; e < 4; ++e) { sb[e] = (short)f2bf(b0[e]); sb[4 + e] = (short)f2bf(b1[e]); }
      *(short8*)(Bs + row * 40 + col) = sb;
    }
    __syncthreads();

    short8 afr[4], bfr[4];
#pragma unroll
    for (int t = 0; t < 4; ++t) {
      afr[t] = *(const short8*)(As + (wm * 64 + t * 16 + l16) * 32 + quad * 8);
      bfr[t] = *(const short8*)(Bs + (wn * 64 + t * 16 + l16) * 40 + quad * 8);
    }
#pragma unroll
    for (int i = 0; i < 4; ++i)
#pragma unroll
      for (int j = 0; j < 4; ++j)
        acc[i][j] = __builtin_amdgcn_mfma_f32_16x16x32_bf16(afr[i], bfr[j], acc[i][j], 0, 0, 0);
  }
}

// ---------------------------------------------------------------------------
// Fused QKV projection. grid = (64, 24): y/8 selects Q/K/V, y%8 = n-block.
// ---------------------------------------------------------------------------
__global__ __launch_bounds__(256, 2)
void qkv_kernel(const u16* __restrict__ xb,
                const float* __restrict__ Wq, const float* __restrict__ Wk, const float* __restrict__ Wv,
                const float* __restrict__ bq, const float* __restrict__ bk, const float* __restrict__ bv,
                u16* __restrict__ Qo, u16* __restrict__ Ko, u16* __restrict__ Vto)
{
  const int mat = blockIdx.y >> 3;
  const int m0  = blockIdx.x * 128;
  const int n0  = (blockIdx.y & 7) * 128;
  const float* W    = (mat == 0) ? Wq : (mat == 1) ? Wk : Wv;
  const float* bias = (mat == 0) ? bq : (mat == 1) ? bk : bv;
  u16* dst          = (mat == 0) ? Qo : (mat == 1) ? Ko : Vto;

  floatx4 acc[4][4];
  gemm_core_async(xb, W, m0, n0, acc);

  const int tid = threadIdx.x;
  const int w = tid >> 6, lane = tid & 63;
  const int wm = w >> 1, wn = w & 1, quad = lane >> 4, l16 = lane & 15;

#pragma unroll
  for (int nt = 0; nt < 4; ++nt) {
    const int n = n0 + wn * 64 + nt * 16 + l16;
    const float bb = bias[n];
    const int h = n >> 6, d = n & 63;
#pragma unroll
    for (int mt = 0; mt < 4; ++mt)
#pragma unroll
      for (int r = 0; r < 4; ++r) {
        const int m = m0 + wm * 64 + mt * 16 + quad * 4 + r;
        const int b = m >> 11, s = m & 2047;
        const float v = acc[mt][nt][r] + bb;
        size_t off;
        if (mat < 2) off = ((size_t)(b * NH + h) * SEQ + s) * DK + d;   // (b,h,s,d)
        else         off = ((size_t)(b * NH + h) * DK + d) * SEQ + s;   // (b,h,d,s)
        dst[off] = f2bf(v);
      }
  }
}

// ---------------------------------------------------------------------------
// Flash attention, causal, exp2-domain, no-rescale online softmax.
// grid = (64 bh, 16 qt-reversed). Block = 128 q-rows, 4 waves x 32 rows.
// l (row-sum) tracked by MFMA with a ones-B-fragment.
// ---------------------------------------------------------------------------
#define AT_STR 72
__global__ __launch_bounds__(256, 2)
void attn_kernel(const u16* __restrict__ Q, const u16* __restrict__ Kx,
                 const u16* __restrict__ Vt, u16* __restrict__ O)
{
  __shared__ short Ks[64 * 64];          // [key][d], chunk-swizzled
  __shared__ short Vs[64 * 64];          // [d][s],   chunk-swizzled
  __shared__ short Ps[4 * 32 * AT_STR];  // per-wave P, padded stride

  const int bh  = blockIdx.x;
  const int qtb = 15 - (int)blockIdx.y;  // heavy blocks dispatched first
  const int q0  = qtb * 128;
  const int tid = threadIdx.x;
  const int w = tid >> 6, lane = tid & 63;
  const int quad = lane >> 4, l16 = lane & 15;
  const int r8 = lane >> 3, c8 = lane & 7;

  const u16* Qh = Q  + (size_t)bh * SEQ * DK;
  const u16* Kh = Kx + (size_t)bh * SEQ * DK;
  const u16* Vh = Vt + (size_t)bh * DK * SEQ;

  // Q fragments (2 frags of 16 rows per wave), held for whole kernel
  short8 qf[2][2];
#pragma unroll
  for (int qp = 0; qp < 2; ++qp) {
    const int qrow = q0 + w * 32 + qp * 16 + l16;
#pragma unroll
    for (int h = 0; h < 2; ++h)
      qf[qp][h] = *(const short8*)(Qh + (size_t)qrow * DK + h * 32 + quad * 8);
  }

  // ones B-fragment: B[n][k] = 1 iff n==0  (row-sum via MFMA)
  short8 vone;
#pragma unroll
  for (int j = 0; j < 8; ++j) vone[j] = (l16 == 0) ? (short)0x3F80 : (short)0;

  floatx4 o[2][4], ls[2];
#pragma unroll
  for (int qp = 0; qp < 2; ++qp) {
    ls[qp] = floatx4{0.f, 0.f, 0.f, 0.f};
#pragma unroll
    for (int dt = 0; dt < 4; ++dt) o[qp][dt] = floatx4{0.f, 0.f, 0.f, 0.f};
  }

  const float SC2 = 0.18033688011f;   // (1/8) * log2(e)
  const int ktmax = 2 * qtb + 2;

  for (int kt = 0; kt < ktmax; ++kt) {
    const int k0 = kt * 64;
    __syncthreads();
    // stage K,V via async, source-side XOR chunk swizzle (dest stays contiguous)
#pragma unroll
    for (int c = 0; c < 2; ++c) {
      const int row8 = w * 16 + c * 8;   // wave-uniform
      const int sw   = (c8 ^ r8) * 8;    // (r8 & 7) == r8
      async_copy16(Kh + (size_t)(k0 + row8 + r8) * DK + sw, Ks + row8 * 64);
      async_copy16(Vh + (size_t)(row8 + r8) * SEQ + k0 + sw, Vs + row8 * 64);
    }
    __syncthreads();

    // K fragments (shared across both q-frags)
    short8 kf[4][2], vf[4][2];
#pragma unroll
    for (int nt = 0; nt < 4; ++nt)
#pragma unroll
      for (int h = 0; h < 2; ++h) {
        kf[nt][h] = *(const short8*)(Ks + (nt * 16 + l16) * 64 + (((h * 4 + quad) ^ (l16 & 7)) * 8));
        vf[nt][h] = *(const short8*)(Vs + (nt * 16 + l16) * 64 + (((h * 4 + quad) ^ (l16 & 7)) * 8));
      }

#pragma unroll
    for (int qp = 0; qp < 2; ++qp) {
      const int frag0 = q0 + w * 32 + qp * 16;
      if (k0 <= frag0 + 15) {            // wave-uniform: skip fully-masked frags
        floatx4 sc[4];
#pragma unroll
        for (int nt = 0; nt < 4; ++nt) {
          floatx4 z = floatx4{0.f, 0.f, 0.f, 0.f};
          z = __builtin_amdgcn_mfma_f32_16x16x32_bf16(qf[qp][0], kf[nt][0], z, 0, 0, 0);
          z = __builtin_amdgcn_mfma_f32_16x16x32_bf16(qf[qp][1], kf[nt][1], z, 0, 0, 0);
          sc[nt] = z;
        }
        const bool diag = (k0 + 63 > frag0);
#pragma unroll
        for (int nt = 0; nt < 4; ++nt)
#pragma unroll
          for (int r = 0; r < 4; ++r) {
            float s = sc[nt][r] * SC2;
            if (diag) {
              const int col = k0 + nt * 16 + l16;
              const int row = frag0 + quad * 4 + r;
              if (col > row) s = -1e30f;
            }
            sc[nt][r] = __builtin_amdgcn_exp2f(s);   // v_exp_f32
          }
        // P: C-layout -> LDS (padded) -> A-layout; wave-private region
        short* Pp = Ps + (w * 32 + qp * 16) * AT_STR;
#pragma unroll
        for (int nt = 0; nt < 4; ++nt)
#pragma unroll
          for (int r = 0; r < 4; ++r)
            Pp[(quad * 4 + r) * AT_STR + nt * 16 + l16] = (short)f2bf(sc[nt][r]);
        short8 pf[2];
#pragma unroll
        for (int h = 0; h < 2; ++h)
          pf[h] = *(const short8*)(Pp + l16 * AT_STR + h * 32 + quad * 8);
        // O += P V  and  l += P 1
#pragma unroll
        for (int dt = 0; dt < 4; ++dt) {
          o[qp][dt] = __builtin_amdgcn_mfma_f32_16x16x32_bf16(pf[0], vf[dt][0], o[qp][dt], 0, 0, 0);
          o[qp][dt] = __builtin_amdgcn_mfma_f32_16x16x32_bf16(pf[1], vf[dt][1], o[qp][dt], 0, 0, 0);
        }
        ls[qp] = __builtin_amdgcn_mfma_f32_16x16x32_bf16(pf[0], vone, ls[qp], 0, 0, 0);
        ls[qp] = __builtin_amdgcn_mfma_f32_16x16x32_bf16(pf[1], vone, ls[qp], 0, 0, 0);
      }
    }
  }

  // epilogue: O'[b, s, h*64+d] bf16; l lives in lanes l16==0 (col 0 of ones-tile)
  const int b = bh >> 4, h = bh & 15;
#pragma unroll
  for (int qp = 0; qp < 2; ++qp) {
    const int frag0 = q0 + w * 32 + qp * 16;
#pragma unroll
    for (int r = 0; r < 4; ++r) {
      const float lv  = __shfl(ls[qp][r], lane & 48);   // broadcast from l16==0 in same quad
      const float inv = 1.0f / fmaxf(lv, 1e-20f);
      const int row   = frag0 + quad * 4 + r;
      const size_t base = ((size_t)b * SEQ + row) * DM + h * DK;
#pragma unroll
      for (int dt = 0; dt < 4; ++dt)
        O[base + dt * 16 + l16] = f2bf(o[qp][dt][r] * inv);
    }
  }
}

// ---------------------------------------------------------------------------
// Output projection: out = O'(bf16) @ Wo^T + bo, fp32 out. grid = (64, 8).
// ---------------------------------------------------------------------------
__global__ __launch_bounds__(256, 2)
void oproj_kernel(const u16* __restrict__ A, const float* __restrict__ Wo,
                  const float* __restrict__ bo, float* __restrict__ out)
{
  const int m0 = blockIdx.x * 128, n0 = blockIdx.y * 128;
  floatx4 acc[4][4];
  gemm_core_async(A, Wo, m0, n0, acc);

  const int tid = threadIdx.x;
  const int w = tid >> 6, lane = tid & 63;
  const int wm = w >> 1, wn = w & 1, quad = lane >> 4, l16 = lane & 15;

#pragma unroll
  for (int nt = 0; nt < 4; ++nt) {
    const int n = n0 + wn * 64 + nt * 16 + l16;
    const float bb = bo[n];
#pragma unroll
    for (int mt = 0; mt < 4; ++mt)
#pragma unroll
      for (int r = 0; r < 4; ++r) {
        const int m = m0 + wm * 64 + mt * 16 + quad * 4 + r;
        out[(size_t)m * DM + n] = acc[mt][nt][r] + bb;
      }
  }
}

extern "C" void kernel_launch(void* const* d_in, const int* in_sizes, int n_in,
                              void* d_out, int out_size, void* d_ws, size_t ws_size,
                              hipStream_t stream)
{
  const float* x  = (const float*)d_in[0];
  const float* Wq = (const float*)d_in[1];
  const float* bq = (const float*)d_in[2];
  const float* Wk = (const float*)d_in[3];
  const float* bk = (const float*)d_in[4];
  const float* Wv = (const float*)d_in[5];
  const float* bv = (const float*)d_in[6];
  const float* Wo = (const float*)d_in[7];
  const float* bo = (const float*)d_in[8];
  float* out = (float*)d_out;

  u16* qws  = (u16*)d_ws;                       // (b,h,s,d)  bf16, 16 MiB
  u16* kws  = qws  + (size_t)M_ROWS * DM;       // (b,h,s,d)  bf16, 16 MiB
  u16* vtws = kws  + (size_t)M_ROWS * DM;       // (b,h,d,s)  bf16, 16 MiB
  u16* xb   = vtws + (size_t)M_ROWS * DM;       // x bf16 / O' bf16 (aliased), 16 MiB
  u16* ows  = xb;                               // xb dead after qkv_kernel

  cvt_kernel <<<dim3(2048), 256, 0, stream>>>(x, xb, (M_ROWS * DM) / 4);
  qkv_kernel <<<dim3(64, 24), 256, 0, stream>>>(xb, Wq, Wk, Wv, bq, bk, bv, qws, kws, vtws);
  attn_kernel<<<dim3(64, 16), 256, 0, stream>>>(qws, kws, vtws, ows);
  oproj_kernel<<<dim3(64, 8), 256, 0, stream>>>(ows, Wo, bo, out);
}

// Round 6
// 275.453 us; speedup vs baseline: 2.1050x; 1.0682x over previous
//
#include <hip/hip_runtime.h>
#include <hip/hip_bf16.h>

typedef __attribute__((ext_vector_type(8))) short short8;
typedef __attribute__((ext_vector_type(4))) short short4v;
typedef __attribute__((ext_vector_type(4))) float floatx4;
typedef unsigned short u16;

#define B_SZ 4
#define NH   16
#define SEQ  2048
#define DM   1024
#define DK   64
#define M_ROWS (B_SZ * SEQ)   // 8192

__device__ __forceinline__ u16 f2bf(float f) {
  unsigned u = __float_as_uint(f);
  u += 0x7fff + ((u >> 16) & 1);   // RNE
  return (u16)(u >> 16);
}

// async global->LDS: dest = wave-uniform base + lane*16B (verified constraint)
__device__ __forceinline__ void async_copy16(const u16* g, const short* lds) {
  __builtin_amdgcn_global_load_lds(
      (const __attribute__((address_space(1))) void*)g,
      (__attribute__((address_space(3))) void*)lds,
      16, 0, 0);
}

// ---------------------------------------------------------------------------
// cvt4: fp32->bf16 for x (y=0) and Wq/Wk/Wv (y=1..3). grid=(1024,4).
// ---------------------------------------------------------------------------
__global__ __launch_bounds__(256)
void cvt4_kernel(const float* __restrict__ x,
                 const float* __restrict__ wq, const float* __restrict__ wk,
                 const float* __restrict__ wv,
                 u16* __restrict__ xb, u16* __restrict__ wb)
{
  const int y = blockIdx.y;
  const float* src; u16* dst; int n4;
  if (y == 0)      { src = x;  dst = xb;                 n4 = (M_ROWS * DM) / 4; }
  else if (y == 1) { src = wq; dst = wb;                 n4 = (DM * DM) / 4; }
  else if (y == 2) { src = wk; dst = wb + DM * DM;       n4 = (DM * DM) / 4; }
  else             { src = wv; dst = wb + 2 * DM * DM;   n4 = (DM * DM) / 4; }
  for (int i = blockIdx.x * 256 + threadIdx.x; i < n4; i += gridDim.x * 256) {
    floatx4 v = ((const floatx4*)src)[i];
    short4v s;
#pragma unroll
    for (int e = 0; e < 4; ++e) s[e] = (short)f2bf(v[e]);
    ((short4v*)dst)[i] = s;
  }
}

__global__ __launch_bounds__(256)
void cvt1_kernel(const float* __restrict__ in, u16* __restrict__ out, int n4)
{
  for (int i = blockIdx.x * 256 + threadIdx.x; i < n4; i += gridDim.x * 256) {
    floatx4 v = ((const floatx4*)in)[i];
    short4v s;
#pragma unroll
    for (int e = 0; e < 4; ++e) s[e] = (short)f2bf(v[e]);
    ((short4v*)out)[i] = s;
  }
}

// ---------------------------------------------------------------------------
// 128x128 GEMM core, both sides bf16 + global_load_lds (m97 structure):
// C = A(MxK bf16 row-major) * Wb^T (Wb NxK bf16 row-major).
// ---------------------------------------------------------------------------
__device__ __forceinline__ void gemm_core_bb(
    const u16* __restrict__ A, const u16* __restrict__ Wb,
    int m0, int n0, floatx4 acc[4][4])
{
  __shared__ short As[128 * 32];
  __shared__ short Bs[128 * 32];

  const int tid  = threadIdx.x;
  const int w    = tid >> 6;
  const int lane = tid & 63;
  const int wm   = w >> 1, wn = w & 1;
  const int quad = lane >> 4, l16 = lane & 15;
  const int r4   = lane >> 2, c4 = lane & 3;

#pragma unroll
  for (int i = 0; i < 4; ++i)
#pragma unroll
    for (int j = 0; j < 4; ++j)
      acc[i][j] = floatx4{0.f, 0.f, 0.f, 0.f};

  for (int kt = 0; kt < (DM >> 5); ++kt) {
    const int kk = kt * 32;
    __syncthreads();
#pragma unroll
    for (int c = 0; c < 2; ++c) {
      const int rowA = w * 32 + c * 16;   // wave-uniform
      async_copy16(A  + (size_t)(m0 + rowA + r4) * DM + kk + c4 * 8, As + rowA * 32);
      async_copy16(Wb + (size_t)(n0 + rowA + r4) * DM + kk + c4 * 8, Bs + rowA * 32);
    }
    __syncthreads();

    short8 afr[4], bfr[4];
#pragma unroll
    for (int t = 0; t < 4; ++t) {
      afr[t] = *(const short8*)(As + (wm * 64 + t * 16 + l16) * 32 + quad * 8);
      bfr[t] = *(const short8*)(Bs + (wn * 64 + t * 16 + l16) * 32 + quad * 8);
    }
#pragma unroll
    for (int i = 0; i < 4; ++i)
#pragma unroll
      for (int j = 0; j < 4; ++j)
        acc[i][j] = __builtin_amdgcn_mfma_f32_16x16x32_bf16(afr[i], bfr[j], acc[i][j], 0, 0, 0);
  }
}

// ---------------------------------------------------------------------------
// Fused QKV projection. grid = (64, 24): y/8 selects Q/K/V, y%8 = n-block.
// Weights pre-converted bf16, packed [3][DM][DM].
// ---------------------------------------------------------------------------
__global__ __launch_bounds__(256, 2)
void qkv_kernel(const u16* __restrict__ xb, const u16* __restrict__ wb,
                const float* __restrict__ bq, const float* __restrict__ bk,
                const float* __restrict__ bv,
                u16* __restrict__ Qo, u16* __restrict__ Ko, u16* __restrict__ Vto)
{
  const int mat = blockIdx.y >> 3;
  const int m0  = blockIdx.x * 128;
  const int n0  = (blockIdx.y & 7) * 128;
  const u16* W      = wb + (size_t)mat * DM * DM;
  const float* bias = (mat == 0) ? bq : (mat == 1) ? bk : bv;
  u16* dst          = (mat == 0) ? Qo : (mat == 1) ? Ko : Vto;

  floatx4 acc[4][4];
  gemm_core_bb(xb, W, m0, n0, acc);

  const int tid = threadIdx.x;
  const int w = tid >> 6, lane = tid & 63;
  const int wm = w >> 1, wn = w & 1, quad = lane >> 4, l16 = lane & 15;

#pragma unroll
  for (int nt = 0; nt < 4; ++nt) {
    const int n = n0 + wn * 64 + nt * 16 + l16;
    const float bb = bias[n];
    const int h = n >> 6, d = n & 63;
#pragma unroll
    for (int mt = 0; mt < 4; ++mt)
#pragma unroll
      for (int r = 0; r < 4; ++r) {
        const int m = m0 + wm * 64 + mt * 16 + quad * 4 + r;
        const int b = m >> 11, s = m & 2047;
        const float v = acc[mt][nt][r] + bb;
        size_t off;
        if (mat < 2) off = ((size_t)(b * NH + h) * SEQ + s) * DK + d;   // (b,h,s,d)
        else         off = ((size_t)(b * NH + h) * DK + d) * SEQ + s;   // (b,h,d,s)
        dst[off] = f2bf(v);
      }
  }
}

// ---------------------------------------------------------------------------
// Flash attention, causal, exp2-domain, no-rescale online softmax.
// grid = (64 bh, 16 qt-reversed). Block = 128 q-rows, 4 waves x 32 rows.
// (unchanged from round 5 — next round's target)
// ---------------------------------------------------------------------------
#define AT_STR 72
__global__ __launch_bounds__(256, 2)
void attn_kernel(const u16* __restrict__ Q, const u16* __restrict__ Kx,
                 const u16* __restrict__ Vt, u16* __restrict__ O)
{
  __shared__ short Ks[64 * 64];
  __shared__ short Vs[64 * 64];
  __shared__ short Ps[4 * 32 * AT_STR];

  const int bh  = blockIdx.x;
  const int qtb = 15 - (int)blockIdx.y;
  const int q0  = qtb * 128;
  const int tid = threadIdx.x;
  const int w = tid >> 6, lane = tid & 63;
  const int quad = lane >> 4, l16 = lane & 15;
  const int r8 = lane >> 3, c8 = lane & 7;

  const u16* Qh = Q  + (size_t)bh * SEQ * DK;
  const u16* Kh = Kx + (size_t)bh * SEQ * DK;
  const u16* Vh = Vt + (size_t)bh * DK * SEQ;

  short8 qf[2][2];
#pragma unroll
  for (int qp = 0; qp < 2; ++qp) {
    const int qrow = q0 + w * 32 + qp * 16 + l16;
#pragma unroll
    for (int h = 0; h < 2; ++h)
      qf[qp][h] = *(const short8*)(Qh + (size_t)qrow * DK + h * 32 + quad * 8);
  }

  short8 vone;
#pragma unroll
  for (int j = 0; j < 8; ++j) vone[j] = (l16 == 0) ? (short)0x3F80 : (short)0;

  floatx4 o[2][4], ls[2];
#pragma unroll
  for (int qp = 0; qp < 2; ++qp) {
    ls[qp] = floatx4{0.f, 0.f, 0.f, 0.f};
#pragma unroll
    for (int dt = 0; dt < 4; ++dt) o[qp][dt] = floatx4{0.f, 0.f, 0.f, 0.f};
  }

  const float SC2 = 0.18033688011f;   // (1/8) * log2(e)
  const int ktmax = 2 * qtb + 2;

  for (int kt = 0; kt < ktmax; ++kt) {
    const int k0 = kt * 64;
    __syncthreads();
#pragma unroll
    for (int c = 0; c < 2; ++c) {
      const int row8 = w * 16 + c * 8;   // wave-uniform
      const int sw   = (c8 ^ r8) * 8;
      async_copy16(Kh + (size_t)(k0 + row8 + r8) * DK + sw, Ks + row8 * 64);
      async_copy16(Vh + (size_t)(row8 + r8) * SEQ + k0 + sw, Vs + row8 * 64);
    }
    __syncthreads();

    short8 kf[4][2], vf[4][2];
#pragma unroll
    for (int nt = 0; nt < 4; ++nt)
#pragma unroll
      for (int h = 0; h < 2; ++h) {
        kf[nt][h] = *(const short8*)(Ks + (nt * 16 + l16) * 64 + (((h * 4 + quad) ^ (l16 & 7)) * 8));
        vf[nt][h] = *(const short8*)(Vs + (nt * 16 + l16) * 64 + (((h * 4 + quad) ^ (l16 & 7)) * 8));
      }

#pragma unroll
    for (int qp = 0; qp < 2; ++qp) {
      const int frag0 = q0 + w * 32 + qp * 16;
      if (k0 <= frag0 + 15) {
        floatx4 sc[4];
#pragma unroll
        for (int nt = 0; nt < 4; ++nt) {
          floatx4 z = floatx4{0.f, 0.f, 0.f, 0.f};
          z = __builtin_amdgcn_mfma_f32_16x16x32_bf16(qf[qp][0], kf[nt][0], z, 0, 0, 0);
          z = __builtin_amdgcn_mfma_f32_16x16x32_bf16(qf[qp][1], kf[nt][1], z, 0, 0, 0);
          sc[nt] = z;
        }
        const bool diag = (k0 + 63 > frag0);
#pragma unroll
        for (int nt = 0; nt < 4; ++nt)
#pragma unroll
          for (int r = 0; r < 4; ++r) {
            float s = sc[nt][r] * SC2;
            if (diag) {
              const int col = k0 + nt * 16 + l16;
              const int row = frag0 + quad * 4 + r;
              if (col > row) s = -1e30f;
            }
            sc[nt][r] = __builtin_amdgcn_exp2f(s);
          }
        short* Pp = Ps + (w * 32 + qp * 16) * AT_STR;
#pragma unroll
        for (int nt = 0; nt < 4; ++nt)
#pragma unroll
          for (int r = 0; r < 4; ++r)
            Pp[(quad * 4 + r) * AT_STR + nt * 16 + l16] = (short)f2bf(sc[nt][r]);
        short8 pf[2];
#pragma unroll
        for (int h = 0; h < 2; ++h)
          pf[h] = *(const short8*)(Pp + l16 * AT_STR + h * 32 + quad * 8);
#pragma unroll
        for (int dt = 0; dt < 4; ++dt) {
          o[qp][dt] = __builtin_amdgcn_mfma_f32_16x16x32_bf16(pf[0], vf[dt][0], o[qp][dt], 0, 0, 0);
          o[qp][dt] = __builtin_amdgcn_mfma_f32_16x16x32_bf16(pf[1], vf[dt][1], o[qp][dt], 0, 0, 0);
        }
        ls[qp] = __builtin_amdgcn_mfma_f32_16x16x32_bf16(pf[0], vone, ls[qp], 0, 0, 0);
        ls[qp] = __builtin_amdgcn_mfma_f32_16x16x32_bf16(pf[1], vone, ls[qp], 0, 0, 0);
      }
    }
  }

  const int b = bh >> 4, h = bh & 15;
#pragma unroll
  for (int qp = 0; qp < 2; ++qp) {
    const int frag0 = q0 + w * 32 + qp * 16;
#pragma unroll
    for (int r = 0; r < 4; ++r) {
      const float lv  = __shfl(ls[qp][r], lane & 48);
      const float inv = 1.0f / fmaxf(lv, 1e-20f);
      const int row   = frag0 + quad * 4 + r;
      const size_t base = ((size_t)b * SEQ + row) * DM + h * DK;
#pragma unroll
      for (int dt = 0; dt < 4; ++dt)
        O[base + dt * 16 + l16] = f2bf(o[qp][dt][r] * inv);
    }
  }
}

// ---------------------------------------------------------------------------
// Output projection: out = O'(bf16) @ Wo_b^T + bo, fp32 out. grid = (64, 8).
// ---------------------------------------------------------------------------
__global__ __launch_bounds__(256, 2)
void oproj_kernel(const u16* __restrict__ A, const u16* __restrict__ Wob,
                  const float* __restrict__ bo, float* __restrict__ out)
{
  const int m0 = blockIdx.x * 128, n0 = blockIdx.y * 128;
  floatx4 acc[4][4];
  gemm_core_bb(A, Wob, m0, n0, acc);

  const int tid = threadIdx.x;
  const int w = tid >> 6, lane = tid & 63;
  const int wm = w >> 1, wn = w & 1, quad = lane >> 4, l16 = lane & 15;

#pragma unroll
  for (int nt = 0; nt < 4; ++nt) {
    const int n = n0 + wn * 64 + nt * 16 + l16;
    const float bb = bo[n];
#pragma unroll
    for (int mt = 0; mt < 4; ++mt)
#pragma unroll
      for (int r = 0; r < 4; ++r) {
        const int m = m0 + wm * 64 + mt * 16 + quad * 4 + r;
        out[(size_t)m * DM + n] = acc[mt][nt][r] + bb;
      }
  }
}

extern "C" void kernel_launch(void* const* d_in, const int* in_sizes, int n_in,
                              void* d_out, int out_size, void* d_ws, size_t ws_size,
                              hipStream_t stream)
{
  const float* x  = (const float*)d_in[0];
  const float* Wq = (const float*)d_in[1];
  const float* bq = (const float*)d_in[2];
  const float* Wk = (const float*)d_in[3];
  const float* bk = (const float*)d_in[4];
  const float* Wv = (const float*)d_in[5];
  const float* bv = (const float*)d_in[6];
  const float* Wo = (const float*)d_in[7];
  const float* bo = (const float*)d_in[8];
  float* out = (float*)d_out;

  // ws (64 MiB): Q, K, Vt, O'  (qws doubles as Wo_b after attn)
  u16* qws  = (u16*)d_ws;                       // (b,h,s,d)  bf16, 16 MiB
  u16* kws  = qws  + (size_t)M_ROWS * DM;       // (b,h,s,d)  bf16, 16 MiB
  u16* vtws = kws  + (size_t)M_ROWS * DM;       // (b,h,d,s)  bf16, 16 MiB
  u16* ows  = vtws + (size_t)M_ROWS * DM;       // O' (b,s,h*d) bf16, 16 MiB

  // d_out doubles as scratch until oproj overwrites all of it:
  //   [0, 16 MiB)  : x bf16
  //   [16, 22 MiB) : Wq/Wk/Wv bf16 packed [3][DM][DM]
  u16* xb = (u16*)d_out;
  u16* wb = xb + (size_t)M_ROWS * DM;
  u16* wo_b = qws;                              // qws dead after attn

  cvt4_kernel<<<dim3(1024, 4), 256, 0, stream>>>(x, Wq, Wk, Wv, xb, wb);
  qkv_kernel <<<dim3(64, 24), 256, 0, stream>>>(xb, wb, bq, bk, bv, qws, kws, vtws);
  attn_kernel<<<dim3(64, 16), 256, 0, stream>>>(qws, kws, vtws, ows);
  cvt1_kernel<<<dim3(1024), 256, 0, stream>>>(Wo, wo_b, (DM * DM) / 4);
  oproj_kernel<<<dim3(64, 8), 256, 0, stream>>>(ows, wo_b, bo, out);
}